// Round 1
// baseline (146.203 us; speedup 1.0000x reference)
//
#include <hip/hip_runtime.h>
#include <stdint.h>

#define BB 8
#define NN 2048
#define KK 32
#define FIN 256
#define FOUT 256
#define CC 512                 // 2*FOUT channels
#define MM (BB*NN)             // 16384 rows
#define RB 32                  // rows per gemm block
#define NBLK (MM/RB)           // 512 gemm blocks
#define LDA 264                // padded LDS row stride (ushorts): 528B -> bank spread

typedef __attribute__((ext_vector_type(8))) short short8;
typedef __attribute__((ext_vector_type(4))) float f32x4;

__device__ __forceinline__ unsigned short f2bf(float f) {
    union { float f; unsigned u; } v; v.f = f;
    unsigned u = v.u;
    return (unsigned short)((u + 0x7FFFu + ((u >> 16) & 1u)) >> 16);  // RNE
}
__device__ __forceinline__ float bf2f(unsigned short s) {
    union { unsigned u; float f; } v; v.u = ((unsigned)s) << 16;
    return v.f;
}

// ---------------- K0: pack weights [512][256] bf16 (out-major) + combined bias
__global__ void k_prep(const float* __restrict__ Wx, const float* __restrict__ Wxb,
                       const float* __restrict__ Wn, const float* __restrict__ Wnb,
                       unsigned short* __restrict__ Wc, float* __restrict__ bc) {
    int gid = blockIdx.x * 256 + threadIdx.x;   // 0..131071
    int o = gid >> 8, k = gid & 255;
    float w = (o < FOUT) ? Wx[o * FIN + k] : Wn[(o - FOUT) * FIN + k];
    Wc[gid] = f2bf(w);
    if (gid < CC) bc[gid] = (gid < FOUT) ? Wxb[gid] : Wnb[gid - FOUT];
}

// ---------------- K1a: x fp32 -> bf16
__global__ void k_conv(const float* __restrict__ x, unsigned short* __restrict__ xb) {
    int gid = blockIdx.x * 256 + threadIdx.x;   // one float4 per thread
    float4 v = ((const float4*)x)[gid];
    ushort4 o; o.x = f2bf(v.x); o.y = f2bf(v.y); o.z = f2bf(v.z); o.w = f2bf(v.w);
    ((ushort4*)xb)[gid] = o;
}

// ---------------- K1b: neighbor gather-mean in bf16 (one wave per output row)
__global__ void k_gather(const unsigned short* __restrict__ xb,
                         const int* __restrict__ idx,
                         unsigned short* __restrict__ xnb) {
    int wave = threadIdx.x >> 6;
    int lane = threadIdx.x & 63;
    int r = blockIdx.x * 4 + wave;              // 0..16383
    int b = r >> 11, n = r & 2047;
    const int* ip = idx + n * KK;               // wave-uniform -> s_load
    const unsigned short* xbb = xb + (size_t)b * NN * FIN + lane * 4;
    float a0 = 0.f, a1 = 0.f, a2 = 0.f, a3 = 0.f;
    #pragma unroll 8
    for (int k = 0; k < KK; ++k) {
        int j = ip[k];
        ushort4 v = *(const ushort4*)(xbb + (size_t)j * FIN);
        a0 += bf2f(v.x); a1 += bf2f(v.y); a2 += bf2f(v.z); a3 += bf2f(v.w);
    }
    const float s = 1.0f / (float)KK;
    ushort4 o; o.x = f2bf(a0 * s); o.y = f2bf(a1 * s); o.z = f2bf(a2 * s); o.w = f2bf(a3 * s);
    *(ushort4*)(xnb + (size_t)r * FIN + lane * 4) = o;
}

// ---------------- K2: fused dual-GEMM (MFMA bf16) + L2-normalize + ReLU
//                  + bf16 h store + per-block BN channel partials
__global__ __launch_bounds__(256, 2)
void k_gemm(const unsigned short* __restrict__ xb,
            const unsigned short* __restrict__ xnb,
            const unsigned short* __restrict__ Wc,
            const float* __restrict__ bc,
            unsigned short* __restrict__ h,
            float* __restrict__ psum, float* __restrict__ psq) {
    __shared__ unsigned short As[2][RB * LDA];   // [0]=x rows, [1]=x_neib rows
    __shared__ float sqpart[4][RB];
    __shared__ float rnorm[RB];

    const int tid  = threadIdx.x;
    const int w    = tid >> 6;
    const int lane = tid & 63;
    const int quad = lane >> 4;
    const int l16  = lane & 15;
    const int r0   = blockIdx.x * RB;

    // stage both A tiles (32 rows x 256 k, bf16) into padded LDS
    {
        const uint4* gs = (const uint4*)(xb  + (size_t)r0 * FIN);
        const uint4* gn = (const uint4*)(xnb + (size_t)r0 * FIN);
        #pragma unroll
        for (int i = 0; i < 4; ++i) {
            int e = tid + i * 256;           // vec8 index, 0..1023
            int row = e >> 5, col8 = e & 31; // 32 vec8 per row
            *(uint4*)&As[0][row * LDA + col8 * 8] = gs[e];
            *(uint4*)&As[1][row * LDA + col8 * 8] = gn[e];
        }
    }
    __syncthreads();

    const unsigned short* A = As[w >> 1];    // waves 0,1: self; 2,3: neighbor
    const int cb = w * 128;                  // this wave's 128 output channels

    f32x4 acc[2][8];
    #pragma unroll
    for (int mt = 0; mt < 2; ++mt)
        #pragma unroll
        for (int nt = 0; nt < 8; ++nt) acc[mt][nt] = (f32x4){0.f, 0.f, 0.f, 0.f};

    const unsigned short* Bp = Wc + (size_t)(cb + l16) * FIN + quad * 8;  // B^T frag base
    const unsigned short* Ap = A + (size_t)l16 * LDA + quad * 8;

    #pragma unroll
    for (int k0 = 0; k0 < FIN; k0 += 32) {
        short8 a0 = *(const short8*)(Ap + k0);
        short8 a1 = *(const short8*)(Ap + 16 * LDA + k0);
        short8 bfr[8];
        #pragma unroll
        for (int nt = 0; nt < 8; ++nt)
            bfr[nt] = *(const short8*)(Bp + (size_t)nt * 16 * FIN + k0);
        #pragma unroll
        for (int nt = 0; nt < 8; ++nt) {
            acc[0][nt] = __builtin_amdgcn_mfma_f32_16x16x32_bf16(a0, bfr[nt], acc[0][nt], 0, 0, 0);
            acc[1][nt] = __builtin_amdgcn_mfma_f32_16x16x32_bf16(a1, bfr[nt], acc[1][nt], 0, 0, 0);
        }
    }

    // bias add + per-row sum of squares (C/D layout: col=l16, row=quad*4+reg)
    float bcv[8];
    #pragma unroll
    for (int nt = 0; nt < 8; ++nt) bcv[nt] = bc[cb + nt * 16 + l16];

    float rsq[2][4] = {{0.f,0.f,0.f,0.f},{0.f,0.f,0.f,0.f}};
    #pragma unroll
    for (int mt = 0; mt < 2; ++mt)
        #pragma unroll
        for (int nt = 0; nt < 8; ++nt)
            #pragma unroll
            for (int r = 0; r < 4; ++r) {
                float v = acc[mt][nt][r] + bcv[nt];
                acc[mt][nt][r] = v;
                rsq[mt][r] += v * v;
            }
    #pragma unroll
    for (int off = 1; off < 16; off <<= 1)
        #pragma unroll
        for (int mt = 0; mt < 2; ++mt)
            #pragma unroll
            for (int r = 0; r < 4; ++r)
                rsq[mt][r] += __shfl_xor(rsq[mt][r], off, 64);
    if (l16 == 0) {
        #pragma unroll
        for (int mt = 0; mt < 2; ++mt)
            #pragma unroll
            for (int r = 0; r < 4; ++r)
                sqpart[w][mt * 16 + quad * 4 + r] = rsq[mt][r];
    }
    __syncthreads();
    if (tid < RB) {
        float tot = sqpart[0][tid] + sqpart[1][tid] + sqpart[2][tid] + sqpart[3][tid];
        rnorm[tid] = 1.0f / fmaxf(sqrtf(tot), 1e-12f);
    }
    __syncthreads();

    // normalize + relu + store h (bf16) + channel partial sums
    float csum[8] = {0.f,0.f,0.f,0.f,0.f,0.f,0.f,0.f};
    float csq [8] = {0.f,0.f,0.f,0.f,0.f,0.f,0.f,0.f};
    #pragma unroll
    for (int mt = 0; mt < 2; ++mt) {
        #pragma unroll
        for (int r = 0; r < 4; ++r) {
            int row = mt * 16 + quad * 4 + r;
            float rn = rnorm[row];
            unsigned short* hp = h + (size_t)(r0 + row) * CC + cb + l16;
            #pragma unroll
            for (int nt = 0; nt < 8; ++nt) {
                float v = fmaxf(acc[mt][nt][r] * rn, 0.0f);
                hp[nt * 16] = f2bf(v);
                csum[nt] += v;
                csq [nt] += v * v;
            }
        }
    }
    #pragma unroll
    for (int off = 16; off < 64; off <<= 1)
        #pragma unroll
        for (int nt = 0; nt < 8; ++nt) {
            csum[nt] += __shfl_xor(csum[nt], off, 64);
            csq [nt] += __shfl_xor(csq [nt], off, 64);
        }
    if (quad == 0) {
        #pragma unroll
        for (int nt = 0; nt < 8; ++nt) {
            int c = cb + nt * 16 + l16;
            psum[(size_t)c * NBLK + blockIdx.x] = csum[nt];
            psq [(size_t)c * NBLK + blockIdx.x] = csq [nt];
        }
    }
}

// ---------------- K3: reduce BN partials -> per-channel scale/shift
__global__ void k_stats(const float* __restrict__ psum, const float* __restrict__ psq,
                        const float* __restrict__ gamma, const float* __restrict__ beta,
                        float* __restrict__ ss) {
    __shared__ float ps[4], pq[4];
    int c = blockIdx.x, t = threadIdx.x;
    float s = psum[(size_t)c * NBLK + t] + psum[(size_t)c * NBLK + 256 + t];
    float q = psq [(size_t)c * NBLK + t] + psq [(size_t)c * NBLK + 256 + t];
    #pragma unroll
    for (int off = 32; off; off >>= 1) { s += __shfl_xor(s, off, 64); q += __shfl_xor(q, off, 64); }
    int w = t >> 6, lane = t & 63;
    if (lane == 0) { ps[w] = s; pq[w] = q; }
    __syncthreads();
    if (t == 0) {
        float S = ps[0] + ps[1] + ps[2] + ps[3];
        float Q = pq[0] + pq[1] + pq[2] + pq[3];
        const float inv = 1.0f / (float)MM;
        float mu  = S * inv;
        float var = fmaxf(Q * inv - mu * mu, 0.0f);
        float sc  = gamma[c] * rsqrtf(var + 1e-5f);
        ss[c]      = sc;
        ss[CC + c] = beta[c] - mu * sc;
    }
}

// ---------------- K4: BN apply, bf16 h -> fp32 out
__global__ void k_apply(const unsigned short* __restrict__ h,
                        const float* __restrict__ ss,
                        float* __restrict__ out) {
    int gid = blockIdx.x * 256 + threadIdx.x;   // 4 elems/thread
    int c0 = (gid * 4) & (CC - 1);
    ushort4 hv = ((const ushort4*)h)[gid];
    float4 sc = *(const float4*)(ss + c0);
    float4 sh = *(const float4*)(ss + CC + c0);
    float4 o;
    o.x = bf2f(hv.x) * sc.x + sh.x;
    o.y = bf2f(hv.y) * sc.y + sh.y;
    o.z = bf2f(hv.z) * sc.z + sh.z;
    o.w = bf2f(hv.w) * sc.w + sh.w;
    ((float4*)out)[gid] = o;
}

extern "C" void kernel_launch(void* const* d_in, const int* in_sizes, int n_in,
                              void* d_out, int out_size, void* d_ws, size_t ws_size,
                              hipStream_t stream) {
    const float* x     = (const float*)d_in[0];
    const int*   idx   = (const int*)  d_in[1];
    const float* Wx_w  = (const float*)d_in[2];
    const float* Wx_b  = (const float*)d_in[3];
    const float* Wn_w  = (const float*)d_in[4];
    const float* Wn_b  = (const float*)d_in[5];
    const float* gamma = (const float*)d_in[6];
    const float* beta  = (const float*)d_in[7];
    float* out = (float*)d_out;

    char* p = (char*)d_ws;
    unsigned short* xb  = (unsigned short*)p; p += (size_t)MM * FIN * 2;   // 8 MB
    unsigned short* xnb = (unsigned short*)p; p += (size_t)MM * FIN * 2;   // 8 MB
    unsigned short* Wc  = (unsigned short*)p; p += (size_t)CC * FIN * 2;   // 256 KB
    float* bc           = (float*)p;          p += (size_t)CC * 4;         // 2 KB
    unsigned short* h   = (unsigned short*)p; p += (size_t)MM * CC * 2;    // 16 MB
    float* psum         = (float*)p;          p += (size_t)CC * NBLK * 4;  // 1 MB
    float* psq          = (float*)p;          p += (size_t)CC * NBLK * 4;  // 1 MB
    float* ss           = (float*)p;          p += (size_t)2 * CC * 4;     // 4 KB

    hipLaunchKernelGGL(k_prep,   dim3(512),  dim3(256), 0, stream, Wx_w, Wx_b, Wn_w, Wn_b, Wc, bc);
    hipLaunchKernelGGL(k_conv,   dim3(4096), dim3(256), 0, stream, x, xb);
    hipLaunchKernelGGL(k_gather, dim3(4096), dim3(256), 0, stream, xb, idx, xnb);
    hipLaunchKernelGGL(k_gemm,   dim3(NBLK), dim3(256), 0, stream, xb, xnb, Wc, bc, h, psum, psq);
    hipLaunchKernelGGL(k_stats,  dim3(CC),   dim3(256), 0, stream, psum, psq, gamma, beta, ss);
    hipLaunchKernelGGL(k_apply,  dim3(8192), dim3(256), 0, stream, h, ss, out);
}

// Round 2
// 141.876 us; speedup vs baseline: 1.0305x; 1.0305x over previous
//
#include <hip/hip_runtime.h>
#include <stdint.h>

#define BB 8
#define NN 2048
#define KK 32
#define FIN 256
#define FOUT 256
#define CC 512                 // 2*FOUT channels
#define MM (BB*NN)             // 16384 rows
#define RB 32                  // rows per gemm block
#define NBLK (MM/RB)           // 512 gemm blocks
#define LDA 264                // padded LDS row stride (ushorts)

typedef __attribute__((ext_vector_type(8))) short short8;
typedef __attribute__((ext_vector_type(4))) float f32x4;

__device__ __forceinline__ unsigned short f2bf(float f) {
    union { float f; unsigned u; } v; v.f = f;
    unsigned u = v.u;
    return (unsigned short)((u + 0x7FFFu + ((u >> 16) & 1u)) >> 16);  // RNE
}
__device__ __forceinline__ float bf2f(unsigned short s) {
    union { unsigned u; float f; } v; v.u = ((unsigned)s) << 16;
    return v.f;
}

// ---------------- K1: fused independent pre-passes.
// blocks [0,4096):    gather-mean (reads fp32 x, XCD-swizzled by batch) -> xnb bf16
// blocks [4096,8192): x fp32 -> bf16 (XCD-swizzled by batch)            -> xb
// blocks [8192,8704): weight pack + bias concat                          -> Wc, bc
__global__ void k_pre(const float* __restrict__ x, const int* __restrict__ idx,
                      const float* __restrict__ Wx, const float* __restrict__ Wxb,
                      const float* __restrict__ Wn, const float* __restrict__ Wnb,
                      unsigned short* __restrict__ xb, unsigned short* __restrict__ xnb,
                      unsigned short* __restrict__ Wc, float* __restrict__ bc) {
    const int blk = blockIdx.x;
    const int tid = threadIdx.x;
    if (blk < 4096) {
        // gather: b = blk&7 pins this block's batch slice (2 MB fp32) to one XCD's L2
        int b = blk & 7;
        int n = (blk >> 3) * 4 + (tid >> 6);    // 4 waves, one row each
        int lane = tid & 63;
        const int* ip = idx + n * KK;
        const float* xbb = x + (size_t)b * NN * FIN + lane * 4;
        float a0 = 0.f, a1 = 0.f, a2 = 0.f, a3 = 0.f;
        #pragma unroll 8
        for (int k = 0; k < KK; ++k) {
            int j = ip[k];
            float4 v = *(const float4*)(xbb + (size_t)j * FIN);
            a0 += v.x; a1 += v.y; a2 += v.z; a3 += v.w;
        }
        const float s = 1.0f / (float)KK;
        ushort4 o; o.x = f2bf(a0 * s); o.y = f2bf(a1 * s); o.z = f2bf(a2 * s); o.w = f2bf(a3 * s);
        *(ushort4*)(xnb + ((size_t)b * NN + n) * FIN + lane * 4) = o;
    } else if (blk < 8192) {
        int c = blk - 4096;
        int b = c & 7, chunk = c >> 3;           // batch-swizzled streaming convert
        size_t f4 = (size_t)b * (NN * FIN / 4) + chunk * 256 + tid;
        float4 v = ((const float4*)x)[f4];
        ushort4 o; o.x = f2bf(v.x); o.y = f2bf(v.y); o.z = f2bf(v.z); o.w = f2bf(v.w);
        ((ushort4*)xb)[f4] = o;
    } else {
        int gid = (blk - 8192) * 256 + tid;      // 0..131071
        int o = gid >> 8, k = gid & 255;
        float w = (o < FOUT) ? Wx[o * FIN + k] : Wn[(o - FOUT) * FIN + k];
        Wc[gid] = f2bf(w);
        if (gid < CC) bc[gid] = (gid < FOUT) ? Wxb[gid] : Wnb[gid - FOUT];
    }
}

// ---------------- K2: fused dual-GEMM (MFMA bf16) + L2-normalize + ReLU
//                  + bf16 h store + per-block BN channel partials
__global__ __launch_bounds__(256, 2)
void k_gemm(const unsigned short* __restrict__ xb,
            const unsigned short* __restrict__ xnb,
            const unsigned short* __restrict__ Wc,
            const float* __restrict__ bc,
            unsigned short* __restrict__ h,
            float* __restrict__ psum, float* __restrict__ psq) {
    __shared__ unsigned short As[2][RB * LDA];   // [0]=x rows, [1]=x_neib rows
    __shared__ float sqpart[4][RB];
    __shared__ float rnorm[RB];

    const int tid  = threadIdx.x;
    const int w    = tid >> 6;
    const int lane = tid & 63;
    const int quad = lane >> 4;
    const int l16  = lane & 15;
    const int r0   = blockIdx.x * RB;

    // stage both A tiles (32 rows x 256 k, bf16) into padded LDS
    {
        const uint4* gs = (const uint4*)(xb  + (size_t)r0 * FIN);
        const uint4* gn = (const uint4*)(xnb + (size_t)r0 * FIN);
        #pragma unroll
        for (int i = 0; i < 4; ++i) {
            int e = tid + i * 256;           // vec8 index, 0..1023
            int row = e >> 5, col8 = e & 31; // 32 vec8 per row
            *(uint4*)&As[0][row * LDA + col8 * 8] = gs[e];
            *(uint4*)&As[1][row * LDA + col8 * 8] = gn[e];
        }
    }
    __syncthreads();

    const unsigned short* A = As[w >> 1];    // waves 0,1: self; 2,3: neighbor
    const int cb = w * 128;                  // this wave's 128 output channels

    f32x4 acc[2][8];
    #pragma unroll
    for (int mt = 0; mt < 2; ++mt)
        #pragma unroll
        for (int nt = 0; nt < 8; ++nt) acc[mt][nt] = (f32x4){0.f, 0.f, 0.f, 0.f};

    const unsigned short* Bp = Wc + (size_t)(cb + l16) * FIN + quad * 8;  // B^T frag base
    const unsigned short* Ap = A + (size_t)l16 * LDA + quad * 8;

    #pragma unroll 2
    for (int k0 = 0; k0 < FIN; k0 += 32) {
        short8 a0 = *(const short8*)(Ap + k0);
        short8 a1 = *(const short8*)(Ap + 16 * LDA + k0);
        short8 bfr[8];
        #pragma unroll
        for (int nt = 0; nt < 8; ++nt)
            bfr[nt] = *(const short8*)(Bp + (size_t)nt * 16 * FIN + k0);
        #pragma unroll
        for (int nt = 0; nt < 8; ++nt) {
            acc[0][nt] = __builtin_amdgcn_mfma_f32_16x16x32_bf16(a0, bfr[nt], acc[0][nt], 0, 0, 0);
            acc[1][nt] = __builtin_amdgcn_mfma_f32_16x16x32_bf16(a1, bfr[nt], acc[1][nt], 0, 0, 0);
        }
    }

    // bias add + per-row sum of squares (C/D layout: col=l16, row=quad*4+reg)
    float bcv[8];
    #pragma unroll
    for (int nt = 0; nt < 8; ++nt) bcv[nt] = bc[cb + nt * 16 + l16];

    float rsq[2][4] = {{0.f,0.f,0.f,0.f},{0.f,0.f,0.f,0.f}};
    #pragma unroll
    for (int mt = 0; mt < 2; ++mt)
        #pragma unroll
        for (int nt = 0; nt < 8; ++nt)
            #pragma unroll
            for (int r = 0; r < 4; ++r) {
                float v = acc[mt][nt][r] + bcv[nt];
                acc[mt][nt][r] = v;
                rsq[mt][r] += v * v;
            }
    #pragma unroll
    for (int off = 1; off < 16; off <<= 1)
        #pragma unroll
        for (int mt = 0; mt < 2; ++mt)
            #pragma unroll
            for (int r = 0; r < 4; ++r)
                rsq[mt][r] += __shfl_xor(rsq[mt][r], off, 64);
    if (l16 == 0) {
        #pragma unroll
        for (int mt = 0; mt < 2; ++mt)
            #pragma unroll
            for (int r = 0; r < 4; ++r)
                sqpart[w][mt * 16 + quad * 4 + r] = rsq[mt][r];
    }
    __syncthreads();
    if (tid < RB) {
        float tot = sqpart[0][tid] + sqpart[1][tid] + sqpart[2][tid] + sqpart[3][tid];
        rnorm[tid] = 1.0f / fmaxf(sqrtf(tot), 1e-12f);
    }
    __syncthreads();

    // normalize + relu + store h (bf16) + channel partial sums
    float csum[8] = {0.f,0.f,0.f,0.f,0.f,0.f,0.f,0.f};
    float csq [8] = {0.f,0.f,0.f,0.f,0.f,0.f,0.f,0.f};
    #pragma unroll
    for (int mt = 0; mt < 2; ++mt) {
        #pragma unroll
        for (int r = 0; r < 4; ++r) {
            int row = mt * 16 + quad * 4 + r;
            float rn = rnorm[row];
            unsigned short* hp = h + (size_t)(r0 + row) * CC + cb + l16;
            #pragma unroll
            for (int nt = 0; nt < 8; ++nt) {
                float v = fmaxf(acc[mt][nt][r] * rn, 0.0f);
                hp[nt * 16] = f2bf(v);
                csum[nt] += v;
                csq [nt] += v * v;
            }
        }
    }
    #pragma unroll
    for (int off = 16; off < 64; off <<= 1)
        #pragma unroll
        for (int nt = 0; nt < 8; ++nt) {
            csum[nt] += __shfl_xor(csum[nt], off, 64);
            csq [nt] += __shfl_xor(csq [nt], off, 64);
        }
    if (quad == 0) {
        #pragma unroll
        for (int nt = 0; nt < 8; ++nt) {
            int c = cb + nt * 16 + l16;
            psum[(size_t)c * NBLK + blockIdx.x] = csum[nt];
            psq [(size_t)c * NBLK + blockIdx.x] = csq [nt];
        }
    }
}

// ---------------- K3: reduce BN partials -> per-channel scale/shift
__global__ void k_stats(const float* __restrict__ psum, const float* __restrict__ psq,
                        const float* __restrict__ gamma, const float* __restrict__ beta,
                        float* __restrict__ ss) {
    __shared__ float ps[4], pq[4];
    int c = blockIdx.x, t = threadIdx.x;
    float s = psum[(size_t)c * NBLK + t] + psum[(size_t)c * NBLK + 256 + t];
    float q = psq [(size_t)c * NBLK + t] + psq [(size_t)c * NBLK + 256 + t];
    #pragma unroll
    for (int off = 32; off; off >>= 1) { s += __shfl_xor(s, off, 64); q += __shfl_xor(q, off, 64); }
    int w = t >> 6, lane = t & 63;
    if (lane == 0) { ps[w] = s; pq[w] = q; }
    __syncthreads();
    if (t == 0) {
        float S = ps[0] + ps[1] + ps[2] + ps[3];
        float Q = pq[0] + pq[1] + pq[2] + pq[3];
        const float inv = 1.0f / (float)MM;
        float mu  = S * inv;
        float var = fmaxf(Q * inv - mu * mu, 0.0f);
        float sc  = gamma[c] * rsqrtf(var + 1e-5f);
        ss[c]      = sc;
        ss[CC + c] = beta[c] - mu * sc;
    }
}

// ---------------- K4: BN apply, bf16 h -> fp32 out
__global__ void k_apply(const unsigned short* __restrict__ h,
                        const float* __restrict__ ss,
                        float* __restrict__ out) {
    int gid = blockIdx.x * 256 + threadIdx.x;   // 4 elems/thread
    int c0 = (gid * 4) & (CC - 1);
    ushort4 hv = ((const ushort4*)h)[gid];
    float4 sc = *(const float4*)(ss + c0);
    float4 sh = *(const float4*)(ss + CC + c0);
    float4 o;
    o.x = bf2f(hv.x) * sc.x + sh.x;
    o.y = bf2f(hv.y) * sc.y + sh.y;
    o.z = bf2f(hv.z) * sc.z + sh.z;
    o.w = bf2f(hv.w) * sc.w + sh.w;
    ((float4*)out)[gid] = o;
}

extern "C" void kernel_launch(void* const* d_in, const int* in_sizes, int n_in,
                              void* d_out, int out_size, void* d_ws, size_t ws_size,
                              hipStream_t stream) {
    const float* x     = (const float*)d_in[0];
    const int*   idx   = (const int*)  d_in[1];
    const float* Wx_w  = (const float*)d_in[2];
    const float* Wx_b  = (const float*)d_in[3];
    const float* Wn_w  = (const float*)d_in[4];
    const float* Wn_b  = (const float*)d_in[5];
    const float* gamma = (const float*)d_in[6];
    const float* beta  = (const float*)d_in[7];
    float* out = (float*)d_out;

    char* p = (char*)d_ws;
    unsigned short* xb  = (unsigned short*)p; p += (size_t)MM * FIN * 2;   // 8 MB
    unsigned short* xnb = (unsigned short*)p; p += (size_t)MM * FIN * 2;   // 8 MB
    unsigned short* Wc  = (unsigned short*)p; p += (size_t)CC * FIN * 2;   // 256 KB
    float* bc           = (float*)p;          p += (size_t)CC * 4;         // 2 KB
    unsigned short* h   = (unsigned short*)p; p += (size_t)MM * CC * 2;    // 16 MB
    float* psum         = (float*)p;          p += (size_t)CC * NBLK * 4;  // 1 MB
    float* psq          = (float*)p;          p += (size_t)CC * NBLK * 4;  // 1 MB
    float* ss           = (float*)p;          p += (size_t)2 * CC * 4;     // 4 KB

    hipLaunchKernelGGL(k_pre,   dim3(8704), dim3(256), 0, stream,
                       x, idx, Wx_w, Wx_b, Wn_w, Wn_b, xb, xnb, Wc, bc);
    hipLaunchKernelGGL(k_gemm,  dim3(NBLK), dim3(256), 0, stream, xb, xnb, Wc, bc, h, psum, psq);
    hipLaunchKernelGGL(k_stats, dim3(CC),   dim3(256), 0, stream, psum, psq, gamma, beta, ss);
    hipLaunchKernelGGL(k_apply, dim3(8192), dim3(256), 0, stream, h, ss, out);
}